// Round 12
// baseline (116.225 us; speedup 1.0000x reference)
//
#include <hip/hip_runtime.h>

typedef _Float16 f16;
typedef f16 f16x2 __attribute__((ext_vector_type(2)));
typedef f16 f16x4 __attribute__((ext_vector_type(4)));
typedef f16 f16x8 __attribute__((ext_vector_type(8)));
typedef float f32x4 __attribute__((ext_vector_type(4)));

constexpr int Mdim = 32768, Ndim = 1024, Kdim = 1024;
constexpr int BM = 256, BN = 256, BK = 64;
constexpr int NT = Kdim / BK;   // 16 K-tiles

static __device__ inline f16x2 cvt2(float a, float b) {
    return __builtin_bit_cast(f16x2, __builtin_amdgcn_cvt_pkrtz(a, b));
}
static __device__ inline f16x4 cvt4(float4 v) {
    f16x2 lo = cvt2(v.x, v.y), hi = cvt2(v.z, v.w);
    return __builtin_shufflevector(lo, hi, 0, 1, 2, 3);
}
static __device__ inline void bar() {          // raw: no vmcnt drain (T4)
    asm volatile("" ::: "memory");
    __builtin_amdgcn_s_barrier();
    asm volatile("" ::: "memory");
}
static __device__ inline void lgkm0() {
    asm volatile("s_waitcnt lgkmcnt(0)" ::: "memory");
}

// out[b,n] = fp32(sum_k fp16(x[b,k]) * fp16(w[n,k])) + bias[n]
// (reference's early-termination mask is always-true: tstat >= 0 > TAU never holds)
//
// m201 8-phase port (4 phases/K-tile), reg-staged for fp32->fp16:
//  P0: cvtWrX_lo(t+1)        | bf(nh0) | bar lgkm0 prio1 16xMFMA q(0,0) prio0 bar
//  P1: cvtWrX_hi, issueX(t+2)| bf(nh1) | ...              q(0,1)
//  P2: cvtWrW_lo(t+1)        | bf(nh0) | ...              q(1,0)
//  P3: cvtWrW_hi, issueW(t+2)| bf(nh1) | ...   q(1,1)  lgkm0 bar  (iter close)
// X lag: issue P1 -> consume next P0/P1 (~3 phases, covers HBM). W: L2-hot.
// vmcnt counted automatically via register deps (never drained to 0 in loop).
__global__ __launch_bounds__(512, 2)
void etrow_gemm(const float* __restrict__ X, const float* __restrict__ W,
                const float* __restrict__ bias, float* __restrict__ out)
{
    __shared__ f16 As[2][BM * BK];   // 32 KB per buffer
    __shared__ f16 Bs[2][BN * BK];   // 128 KB total -> 1 block/CU

    // bijective XCD-aware swizzle (512 blocks, 64 per XCD)
    const int bid = blockIdx.x;
    const int cpx = gridDim.x >> 3;
    const int wg  = (bid & 7) * cpx + (bid >> 3);
    const int mIdx = wg >> 2;        // 4 n-tiles, n fastest
    const int nIdx = wg & 3;

    const int tid  = threadIdx.x;
    const int lane = tid & 63;
    const int wave = tid >> 6;            // 0..7
    const int wr   = (wave >> 2) * 128;   // 2m x 4n waves, wave tile 128x64
    const int wc   = (wave & 3) * 64;

    const int r0 = tid >> 4;    // staging row within 32-row group (R5 layout:
    const int c4 = tid & 15;    //   row = p*32+r0, 0-conflict verified)

    const float* xthr = X + (size_t)mIdx * BM * Kdim + r0 * Kdim + c4 * 4;
    const float* wthr = W + (size_t)nIdx * BN * Kdim + r0 * Kdim + c4 * 4;
    const int wby = (r0 * 128 + c4 * 8) ^ ((r0 & 7) << 4);  // +p*4096, +buf
    // fragment slot: swizzle XORed at build (R8 lesson: s*64 toggles via ^)
    const int slot  = ((lane >> 4) * 16) ^ ((lane & 7) << 4);
    const int abyte = (wr + (lane & 15)) * 128 + slot;
    const int bbyte = (wc + (lane & 15)) * 128 + slot;
    char* const Ab = (char*)&As[0][0];
    char* const Bb = (char*)&Bs[0][0];

    float4 SX[8], SW[8];        // one in-flight K-tile per leg (64 VGPR)
    f32x4 acc[8][4] = {};       // 128 AGPR

    auto issueX = [&](int kt) {
        const float* p = xthr + kt * BK;
        #pragma unroll
        for (int q = 0; q < 8; ++q)
            SX[q] = *(const float4*)(p + (size_t)q * 32 * Kdim);
    };
    auto issueW = [&](int kt) {
        const float* p = wthr + kt * BK;
        #pragma unroll
        for (int q = 0; q < 8; ++q)
            SW[q] = *(const float4*)(p + (size_t)q * 32 * Kdim);
    };
    auto cvtWrX = [&](int off, int half) {   // 4 rows (p = half*4..+3)
        #pragma unroll
        for (int q = half * 4; q < half * 4 + 4; ++q)
            *(f16x4*)(Ab + off + wby + q * 4096) = cvt4(SX[q]);
    };
    auto cvtWrW = [&](int off, int half) {
        #pragma unroll
        for (int q = half * 4; q < half * 4 + 4; ++q)
            *(f16x4*)(Bb + off + wby + q * 4096) = cvt4(SW[q]);
    };

    f16x8 bf[2][2];             // pre-read B frags for one n-half (16 VGPR)
    auto bfRead = [&](int co, int nh) {
        #pragma unroll
        for (int s = 0; s < 2; ++s)
            #pragma unroll
            for (int n = 0; n < 2; ++n)
                bf[s][n] = *(const f16x8*)
                    (Bb + co + ((bbyte + (nh * 2 + n) * 2048) ^ (s << 6)));
    };
    auto quad = [&](int co, int mh, int nh) {   // 16 MFMA, af read inline
        #pragma unroll
        for (int s = 0; s < 2; ++s)
            #pragma unroll
            for (int m = 0; m < 4; ++m) {
                f16x8 af = *(const f16x8*)
                    (Ab + co + ((abyte + (mh * 4 + m) * 2048) ^ (s << 6)));
                #pragma unroll
                for (int n = 0; n < 2; ++n)
                    acc[mh * 4 + m][nh * 2 + n] =
                        __builtin_amdgcn_mfma_f32_16x16x32_f16(
                            af, bf[s][n], acc[mh * 4 + m][nh * 2 + n], 0, 0, 0);
            }
    };

    // prologue: tile 0 staged (one cold vmcnt stall); tile 1 in flight
    issueX(0); issueW(0);
    cvtWrX(0, 0); cvtWrX(0, 1);
    cvtWrW(0, 0); cvtWrW(0, 1);
    issueX(1); issueW(1);
    lgkm0();
    bar();

    for (int t = 0; t < NT; ++t) {
        const int co = (t & 1) << 15;     // 32 KB buffer stride
        const int no = co ^ 32768;
        const bool h1 = t + 1 < NT, h2 = t + 2 < NT;

        // P0
        if (h1) cvtWrX(no, 0);
        bfRead(co, 0);
        bar(); lgkm0();
        __builtin_amdgcn_s_setprio(1); quad(co, 0, 0); __builtin_amdgcn_s_setprio(0);
        bar();
        // P1
        if (h1) cvtWrX(no, 1);
        if (h2) issueX(t + 2);            // WAR after cvtWrX reads; 3-phase lag
        bfRead(co, 1);
        bar(); lgkm0();
        __builtin_amdgcn_s_setprio(1); quad(co, 0, 1); __builtin_amdgcn_s_setprio(0);
        bar();
        // P2
        if (h1) cvtWrW(no, 0);
        bfRead(co, 0);
        bar(); lgkm0();
        __builtin_amdgcn_s_setprio(1); quad(co, 1, 0); __builtin_amdgcn_s_setprio(0);
        bar();
        // P3
        if (h1) cvtWrW(no, 1);
        if (h2) issueW(t + 2);
        bfRead(co, 1);
        bar(); lgkm0();
        __builtin_amdgcn_s_setprio(1); quad(co, 1, 1); __builtin_amdgcn_s_setprio(0);
        lgkm0();                          // drain our writes to nxt + reads of cur
        bar();                            // iteration boundary
    }

    // epilogue: C/D layout col = lane&15, row = (lane>>4)*4 + reg (m89-verified)
    const int col0  = nIdx * BN + wc + (lane & 15);
    const int rbase = mIdx * BM + wr + (lane >> 4) * 4;
    float bv[4];
    #pragma unroll
    for (int n = 0; n < 4; ++n) bv[n] = bias[col0 + n * 16];

    #pragma unroll
    for (int m = 0; m < 8; ++m) {
        #pragma unroll
        for (int j = 0; j < 4; ++j) {
            const int row = rbase + m * 16 + j;
            float* o = out + (size_t)row * Ndim + col0;
            #pragma unroll
            for (int n = 0; n < 4; ++n)
                o[n * 16] = acc[m][n][j] + bv[n];
        }
    }
}

extern "C" void kernel_launch(void* const* d_in, const int* in_sizes, int n_in,
                              void* d_out, int out_size, void* d_ws, size_t ws_size,
                              hipStream_t stream) {
    const float* X  = (const float*)d_in[0];
    const float* W  = (const float*)d_in[1];
    const float* bs = (const float*)d_in[2];
    float* out = (float*)d_out;
    const int grid = (Mdim / BM) * (Ndim / BN);   // 512 blocks
    etrow_gemm<<<grid, 512, 0, stream>>>(X, W, bs, out);
}

// Round 13
// 102.737 us; speedup vs baseline: 1.1313x; 1.1313x over previous
//
#include <hip/hip_runtime.h>

typedef _Float16 f16;
typedef f16 f16x2 __attribute__((ext_vector_type(2)));
typedef f16 f16x4 __attribute__((ext_vector_type(4)));
typedef f16 f16x8 __attribute__((ext_vector_type(8)));
typedef float f32x4 __attribute__((ext_vector_type(4)));

constexpr int Mdim = 32768, Ndim = 1024, Kdim = 1024;
constexpr int BM = 256, BN = 256, BK = 64;
constexpr int NT = Kdim / BK;   // 16 K-steps

static __device__ inline f16x2 cvt2(float a, float b) {
    return __builtin_bit_cast(f16x2, __builtin_amdgcn_cvt_pkrtz(a, b));
}
static __device__ inline f16x4 cvt4(float4 v) {
    f16x2 lo = cvt2(v.x, v.y), hi = cvt2(v.z, v.w);
    return __builtin_shufflevector(lo, hi, 0, 1, 2, 3);
}
static __device__ inline void bar() {          // raw: no vmcnt drain
    asm volatile("" ::: "memory");
    __builtin_amdgcn_s_barrier();
    asm volatile("" ::: "memory");
}
static __device__ inline void lgkm0() {
    asm volatile("s_waitcnt lgkmcnt(0)" ::: "memory");
}

// out[b,n] = fp32(sum_k fp16(x[b,k]) * fp16(w[n,k])) + bias[n]
// (reference's early-termination mask is always-true: tstat >= 0 > TAU never holds)
//
// R13 = R5 with COMPUTE-FIRST / STAGE-AFTER issue order. Key ISA fact: DS ops
// retire IN ORDER per wave, so any lgkm wait for a fragment ds_read also
// drains every OLDER staging ds_write. R5 staged first -> serial chain
// {vmcnt -> cvt -> 16 writes -> frag reads -> MFMA} = 7257 cyc/step. Here:
// frag reads are the oldest lgkm ops each step (their counted waits skip the
// younger writes); staging sits after the MFMA clusters, drained only by the
// end-of-step lgkm0 (~150 cyc exposed instead of ~4500).
__global__ __launch_bounds__(512, 2)
void etrow_gemm(const float* __restrict__ X, const float* __restrict__ W,
                const float* __restrict__ bias, float* __restrict__ out)
{
    __shared__ f16 As[2][BM * BK];   // 32 KB per buffer
    __shared__ f16 Bs[2][BN * BK];   // 128 KB total -> 1 block/CU

    // bijective XCD-aware swizzle (512 blocks, 64 per XCD)
    const int bid = blockIdx.x;
    const int cpx = gridDim.x >> 3;
    const int wg  = (bid & 7) * cpx + (bid >> 3);
    const int mIdx = wg >> 2;        // 4 n-tiles, n fastest
    const int nIdx = wg & 3;

    const int tid  = threadIdx.x;
    const int lane = tid & 63;
    const int wave = tid >> 6;            // 0..7
    const int wr   = (wave >> 2) * 128;   // 2m x 4n waves, wave tile 128x64
    const int wc   = (wave & 3) * 64;

    const int r0 = tid >> 4;    // 0..31 staging row (R5 layout, 0 conflicts)
    const int c4 = tid & 15;

    const float* xthr = X + (size_t)mIdx * BM * Kdim + r0 * Kdim + c4 * 4;
    const float* wthr = W + (size_t)nIdx * BN * Kdim + r0 * Kdim + c4 * 4;
    const int wby = (r0 * 128 + c4 * 8) ^ ((r0 & 7) << 4);  // +q*4096 +buf
    const int aby = ((wr + (lane & 15)) * 128 + (lane >> 4) * 16) ^ ((lane & 7) << 4);
    const int bby = ((wc + (lane & 15)) * 128 + (lane >> 4) * 16) ^ ((lane & 7) << 4);
    char* const Ab = (char*)&As[0][0];
    char* const Bb = (char*)&Bs[0][0];

    float4 S[8];                // ONE shared staging set, time-shared A/B legs
    f32x4 acc[8][4] = {};
    f16x8 af[8], bf[4];         // fragment regs for one K=32 sub-step

    auto loadA = [&](int kt) {
        const float* p = xthr + kt * BK;
        #pragma unroll
        for (int q = 0; q < 8; ++q)
            S[q] = *(const float4*)(p + (size_t)q * 32 * Kdim);
    };
    auto loadB = [&](int kt) {
        const float* p = wthr + kt * BK;
        #pragma unroll
        for (int q = 0; q < 8; ++q)
            S[q] = *(const float4*)(p + (size_t)q * 32 * Kdim);
    };
    auto cvtWrite = [&](char* lds) {    // consume S -> f16 LDS (frees S)
        #pragma unroll
        for (int q = 0; q < 8; ++q)
            *(f16x4*)(lds + wby + q * 4096) = cvt4(S[q]);
    };

    auto readFrags = [&](int co, int s) {   // 12 ds_reads, issued contiguously
        const int kx = s << 6;              // ^64 toggles K-half inside swizzle
        #pragma unroll
        for (int i = 0; i < 8; ++i)
            af[i] = *(const f16x8*)(Ab + co + ((aby + i * 2048) ^ kx));
        #pragma unroll
        for (int j = 0; j < 4; ++j)
            bf[j] = *(const f16x8*)(Bb + co + ((bby + j * 2048) ^ kx));
    };
    auto mfmaSub = [&]() {                  // 32 MFMA on current frags
        #pragma unroll
        for (int i = 0; i < 8; ++i)
            #pragma unroll
            for (int j = 0; j < 4; ++j)
                acc[i][j] = __builtin_amdgcn_mfma_f32_16x16x32_f16(
                    af[i], bf[j], acc[i][j], 0, 0, 0);
    };

    // prologue: tile 0 staged; A(1) in flight across the barrier
    loadA(0); cvtWrite(Ab);
    loadB(0); cvtWrite(Bb);
    loadA(1);
    lgkm0();
    bar();

    for (int t = 0; t < NT; ++t) {
        const int co = (t & 1) << 15;     // 32 KB buffer stride
        const int no = co ^ 32768;
        const bool h1 = t + 1 < NT, h2 = t + 2 < NT;

        readFrags(co, 0);                 // oldest lgkm ops this step
        mfmaSub();                        // s0: waits count ONLY these reads
        if (h1) { cvtWrite(Ab + no);      // S=A(t+1): vmcnt had ~1100cyc cover
                  loadB(t + 1); }         // reuse S (WAR); consumed ~700cyc later
        readFrags(co, 1);                 // drains A-writes (retired during s0)
        mfmaSub();                        // s1
        if (h1) { cvtWrite(Bb + no); }    // W L2-hot; mostly covered
        if (h2) { loadA(t + 2); }         // in flight across the raw barrier
        lgkm0();                          // publish writes (~150cyc exposed)
        bar();
    }

    // epilogue: C/D layout col = lane&15, row = (lane>>4)*4 + reg (m89-verified)
    const int col0  = nIdx * BN + wc + (lane & 15);
    const int rbase = mIdx * BM + wr + (lane >> 4) * 4;
    float bv[4];
    #pragma unroll
    for (int n = 0; n < 4; ++n) bv[n] = bias[col0 + n * 16];

    #pragma unroll
    for (int m = 0; m < 8; ++m) {
        #pragma unroll
        for (int j = 0; j < 4; ++j) {
            const int row = rbase + m * 16 + j;
            float* o = out + (size_t)row * Ndim + col0;
            #pragma unroll
            for (int n = 0; n < 4; ++n)
                o[n * 16] = acc[m][n][j] + bv[n];
        }
    }
}

extern "C" void kernel_launch(void* const* d_in, const int* in_sizes, int n_in,
                              void* d_out, int out_size, void* d_ws, size_t ws_size,
                              hipStream_t stream) {
    const float* X  = (const float*)d_in[0];
    const float* W  = (const float*)d_in[1];
    const float* bs = (const float*)d_in[2];
    float* out = (float*)d_out;
    const int grid = (Mdim / BM) * (Ndim / BN);   // 512 blocks
    etrow_gemm<<<grid, 512, 0, stream>>>(X, W, bs, out);
}